// Round 6
// baseline (570.045 us; speedup 1.0000x reference)
//
#include <hip/hip_runtime.h>
#include <stdint.h>

typedef short bf16x8 __attribute__((ext_vector_type(8)));
typedef float f32x4 __attribute__((ext_vector_type(4)));
typedef unsigned short u16;
typedef unsigned int u32;

#define MFMA(a, b, c) __builtin_amdgcn_mfma_f32_16x16x32_bf16(a, b, c, 0, 0, 0)

#if __has_builtin(__builtin_amdgcn_exp2f)
#define EXP2F(x) __builtin_amdgcn_exp2f(x)
#else
#define EXP2F(x) exp2f(x)
#endif
#if __has_builtin(__builtin_amdgcn_rcpf)
#define RCPF(x) __builtin_amdgcn_rcpf(x)
#else
#define RCPF(x) (1.0f / (x))
#endif

// f32->bf16 round-half-up (0.5 ulp; finite inputs). 2 VALU ops.
__device__ __forceinline__ u16 f2bf(float f) {
  return (u16)((__builtin_bit_cast(u32, f) + 0x8000u) >> 16);
}
// pack two f32 -> bf16x2 in one u32 (half-up). ~4 VALU ops.
__device__ __forceinline__ u32 pkbf(float a, float b) {
  const u32 ua = __builtin_bit_cast(u32, a) + 0x8000u;
  const u32 ub = __builtin_bit_cast(u32, b) + 0x8000u;
  return (ua >> 16) | (ub & 0xFFFF0000u);
}

// ---------------------------------------------------------------------------
// Bulk f32 -> bf16 conversion, two segments per launch (b may be null).
// 8 elems/thread: 32B read -> 16B write, fully coalesced.
// ---------------------------------------------------------------------------
__global__ __launch_bounds__(256) void convert2(const float* __restrict__ a,
                                                u16* __restrict__ da, int na8,
                                                const float* __restrict__ b,
                                                u16* __restrict__ db, int nb8) {
  const int i = blockIdx.x * 256 + (int)threadIdx.x;
  if (i < na8) {
    const float4 f0 = *(const float4*)(a + (size_t)i * 8);
    const float4 f1 = *(const float4*)(a + (size_t)i * 8 + 4);
    const uint4 v = {pkbf(f0.x, f0.y), pkbf(f0.z, f0.w), pkbf(f1.x, f1.y), pkbf(f1.z, f1.w)};
    *(uint4*)(da + (size_t)i * 8) = v;
  }
  if (b != nullptr && i < nb8) {
    const float4 f0 = *(const float4*)(b + (size_t)i * 8);
    const float4 f1 = *(const float4*)(b + (size_t)i * 8 + 4);
    const uint4 v = {pkbf(f0.x, f0.y), pkbf(f0.z, f0.w), pkbf(f1.x, f1.y), pkbf(f1.z, f1.w)};
    *(uint4*)(db + (size_t)i * 8) = v;
  }
}

// ---------------------------------------------------------------------------
// NT GEMM: out[m,n] = oscale * sum_k A[m,k]*W[n,k]; M=8192, N=K=1024, bf16 in.
// 128x128 tile, BK=64, 4 waves, 4x4 16x16x32 MFMA tiles/wave. LDS 8-elem
// blocks XOR-swizzled by (row&7): conflict-free ds_read_b128.
// MODE 0: row-major f32 out (final projection)
// MODE 1: per-head bf16 out[((b*16+h)*2048+nr)*64 + d]           (Q, K)
// MODE 2: per-head transposed bf16 out[((b*16+h)*64+d)*2048+nr]  (V^T)
// ---------------------------------------------------------------------------
template <int MODE, typename OutT>
__global__ __launch_bounds__(256, 2) void gemm_bt(const u16* __restrict__ A,
                                                  const u16* __restrict__ W,
                                                  OutT* __restrict__ out, float oscale) {
  __shared__ u16 smA[128 * 64];
  __shared__ u16 smB[128 * 64];
  const int tid = (int)threadIdx.x;
  const int w = tid >> 6, l = tid & 63;
  const int la = l & 15, q = l >> 4;
  const int m0 = blockIdx.x * 128, n0 = blockIdx.y * 128;
  const int wm = w >> 1, wn = w & 1;

  f32x4 acc[4][4];
#pragma unroll
  for (int i = 0; i < 4; ++i)
#pragma unroll
    for (int j = 0; j < 4; ++j) acc[i][j] = (f32x4){0.f, 0.f, 0.f, 0.f};

  for (int kk = 0; kk < 16; ++kk) {
    __syncthreads();
#pragma unroll
    for (int jj = 0; jj < 4; ++jj) {
      const int idx = jj * 256 + tid;
      const int row = idx >> 3, blk = idx & 7;
      const bf16x8 va = *(const bf16x8*)(A + (size_t)(m0 + row) * 1024 + kk * 64 + blk * 8);
      const bf16x8 vb = *(const bf16x8*)(W + (size_t)(n0 + row) * 1024 + kk * 64 + blk * 8);
      *(bf16x8*)(smA + row * 64 + ((blk ^ (row & 7)) * 8)) = va;
      *(bf16x8*)(smB + row * 64 + ((blk ^ (row & 7)) * 8)) = vb;
    }
    __syncthreads();
#pragma unroll
    for (int ks = 0; ks < 2; ++ks) {
      bf16x8 af[4], bfr[4];
#pragma unroll
      for (int im = 0; im < 4; ++im)
        af[im] = *(const bf16x8*)(smA + (wm * 64 + im * 16 + la) * 64 +
                                  (((ks * 4 + q) ^ (la & 7)) * 8));
#pragma unroll
      for (int in = 0; in < 4; ++in)
        bfr[in] = *(const bf16x8*)(smB + (wn * 64 + in * 16 + la) * 64 +
                                   (((ks * 4 + q) ^ (la & 7)) * 8));
#pragma unroll
      for (int im = 0; im < 4; ++im)
#pragma unroll
        for (int in = 0; in < 4; ++in)
          acc[im][in] = MFMA(af[im], bfr[in], acc[im][in]);
    }
  }

  // epilogue: C/D layout col = la (n), row = q*4 + r (m)
#pragma unroll
  for (int im = 0; im < 4; ++im) {
    const int mbase = m0 + wm * 64 + im * 16 + q * 4;
#pragma unroll
    for (int in = 0; in < 4; ++in) {
      const int n = n0 + wn * 64 + in * 16 + la;
      if (MODE == 2) {
        const int b = mbase >> 11, nr = mbase & 2047;
        const int h = n >> 6, d = n & 63;
        uint2 val;
        val.x = pkbf(acc[im][in][0] * oscale, acc[im][in][1] * oscale);
        val.y = pkbf(acc[im][in][2] * oscale, acc[im][in][3] * oscale);
        *(uint2*)((u16*)out + ((size_t)((b * 16 + h) * 64 + d)) * 2048 + nr) = val;
      } else if (MODE == 0) {
#pragma unroll
        for (int r = 0; r < 4; ++r)
          ((float*)out)[(size_t)(mbase + r) * 1024 + n] = acc[im][in][r] * oscale;
      } else {
#pragma unroll
        for (int r = 0; r < 4; ++r) {
          const int mm = mbase + r;
          const int b = mm >> 11, nr = mm & 2047;
          const int h = n >> 6, d = n & 63;
          ((u16*)out)[((size_t)((b * 16 + h) * 2048 + nr)) * 64 + d] = f2bf(acc[im][in][r] * oscale);
        }
      }
    }
  }
}

// ---------------------------------------------------------------------------
// Flash attention. Grid (16 q-tiles, 64 b*h). Block 256 (4 waves).
// Q pre-scaled by log2(e)/sqrt(64) in its projection epilogue -> S is in
// log2-domain directly. S^T = K·Q^T (A=Kfrag, B=Qfrag): lane holds 4
// consecutive j -> packed 8B P writes. smP halved (j-halves processed
// exp->PV sequentially): LDS = 48KB -> 3 blocks/CU. smP rows are
// wave-private -> no barrier between P write and PV read (DS is in-order
// per wave). alpha/l broadcast via __shfl.
// ---------------------------------------------------------------------------
__global__ __launch_bounds__(256, 3) void attn_kernel(const u16* __restrict__ Qh,
                                                      const u16* __restrict__ Kh,
                                                      const u16* __restrict__ VT,
                                                      u16* __restrict__ ctx) {
  __shared__ u16 smK[128 * 64];  // K tile, swizzled ^(row&7), stride 64
  __shared__ u16 smV[64 * 128];  // V^T tile, swizzled ^(row&15), stride 128
  __shared__ u16 smP[128 * 64];  // P j-half (i x 64), blocks swizzled ^(i&7)

  const int tid = (int)threadIdx.x;
  const int w = tid >> 6, l = tid & 63;
  const int la = l & 15, q = l >> 4;
  const int qt = blockIdx.x, bh = blockIdx.y;
  const u16* Qp = Qh + (size_t)bh * (2048 * 64);
  const u16* Kp = Kh + (size_t)bh * (2048 * 64);
  const u16* Vp = VT + (size_t)bh * (64 * 2048);

  // Q fragments (B-operand: n = lane&15 -> q-row, k = q*8+j)
  bf16x8 qf[2][2];
#pragma unroll
  for (int ic = 0; ic < 2; ++ic)
#pragma unroll
    for (int ks = 0; ks < 2; ++ks)
      qf[ic][ks] = *(const bf16x8*)(Qp + (size_t)(qt * 128 + w * 32 + ic * 16 + la) * 64 +
                                    ks * 32 + q * 8);

  f32x4 accO[2][4];
#pragma unroll
  for (int ic = 0; ic < 2; ++ic)
#pragma unroll
    for (int dc = 0; dc < 4; ++dc) accO[ic][dc] = (f32x4){0.f, 0.f, 0.f, 0.f};
  float m_[2] = {-__builtin_inff(), -__builtin_inff()};
  float l_[2] = {0.f, 0.f};
  float alpha_[2];

  for (int kt = 0; kt < 16; ++kt) {
    __syncthreads();  // prior-iter smK/smV reads done before restage
#pragma unroll
    for (int jj = 0; jj < 4; ++jj) {
      const int idx = jj * 256 + tid;
      const int kr = idx >> 3, kb = idx & 7;  // K tile: 128 rows x 64 k
      const bf16x8 vk = *(const bf16x8*)(Kp + (size_t)(kt * 128 + kr) * 64 + kb * 8);
      *(bf16x8*)(smK + kr * 64 + ((kb ^ (kr & 7)) * 8)) = vk;
      const int vr = idx >> 4, vb = idx & 15;  // V^T tile: 64 rows (d) x 128 j
      const bf16x8 vv = *(const bf16x8*)(Vp + (size_t)vr * 2048 + kt * 128 + vb * 8);
      *(bf16x8*)(smV + vr * 128 + ((vb ^ (vr & 15)) * 8)) = vv;
    }
    __syncthreads();

    // S^T tiles (log2-domain): m = j (8 chunks), n = i (wave's 2 chunks)
    f32x4 st[2][8];
#pragma unroll
    for (int ic = 0; ic < 2; ++ic)
#pragma unroll
      for (int jc = 0; jc < 8; ++jc) st[ic][jc] = (f32x4){0.f, 0.f, 0.f, 0.f};
#pragma unroll
    for (int ks = 0; ks < 2; ++ks) {
      bf16x8 kf[8];
#pragma unroll
      for (int jc = 0; jc < 8; ++jc)
        kf[jc] = *(const bf16x8*)(smK + (jc * 16 + la) * 64 +
                                  (((ks * 4 + q) ^ (la & 7)) * 8));
#pragma unroll
      for (int jc = 0; jc < 8; ++jc)
#pragma unroll
        for (int ic = 0; ic < 2; ++ic)
          st[ic][jc] = MFMA(kf[jc], qf[ic][ks], st[ic][jc]);
    }

    // row max + alpha (full j-range); lane owns row i = w*32+ic*16+la
#pragma unroll
    for (int ic = 0; ic < 2; ++ic) {
      float mx = -__builtin_inff();
#pragma unroll
      for (int jc = 0; jc < 8; ++jc)
#pragma unroll
        for (int r = 0; r < 4; ++r) mx = fmaxf(mx, st[ic][jc][r]);
      mx = fmaxf(mx, __shfl_xor(mx, 16));
      mx = fmaxf(mx, __shfl_xor(mx, 32));
      const float mnew = fmaxf(m_[ic], mx);
      alpha_[ic] = EXP2F(m_[ic] - mnew);
      m_[ic] = mnew;
    }
    // rescale O (O rows q*4+r; alpha for row base+t lives in lane t<16)
#pragma unroll
    for (int ic = 0; ic < 2; ++ic)
#pragma unroll
      for (int r = 0; r < 4; ++r) {
        const float a = __shfl(alpha_[ic], q * 4 + r);
#pragma unroll
        for (int dc = 0; dc < 4; ++dc) accO[ic][dc][r] *= a;
      }

    float rs[2] = {0.f, 0.f};
#pragma unroll
    for (int hh = 0; hh < 2; ++hh) {
      // exp + pack this j-half into smP
#pragma unroll
      for (int ic = 0; ic < 2; ++ic) {
        const int i = w * 32 + ic * 16 + la;
#pragma unroll
        for (int jc4 = 0; jc4 < 4; ++jc4) {
          const int jcg = hh * 4 + jc4;
          const float p0 = EXP2F(st[ic][jcg][0] - m_[ic]);
          const float p1 = EXP2F(st[ic][jcg][1] - m_[ic]);
          const float p2 = EXP2F(st[ic][jcg][2] - m_[ic]);
          const float p3 = EXP2F(st[ic][jcg][3] - m_[ic]);
          rs[ic] += (p0 + p1) + (p2 + p3);
          uint2 val;
          val.x = pkbf(p0, p1);
          val.y = pkbf(p2, p3);
          const int blk = (jc4 * 2 + (q >> 1)) ^ (la & 7);
          *(uint2*)(smP + i * 64 + blk * 8 + (q & 1) * 4) = val;
        }
      }
      // PV over this half (smP rows wave-private; per-wave DS order suffices)
#pragma unroll
      for (int ks2 = 0; ks2 < 2; ++ks2) {
        const int ks = hh * 2 + ks2;
        bf16x8 pf[2], vf[4];
#pragma unroll
        for (int ic = 0; ic < 2; ++ic)
          pf[ic] = *(const bf16x8*)(smP + (w * 32 + ic * 16 + la) * 64 +
                                    (((ks2 * 4 + q) ^ (la & 7)) * 8));
#pragma unroll
        for (int dc = 0; dc < 4; ++dc)
          vf[dc] = *(const bf16x8*)(smV + (dc * 16 + la) * 128 +
                                    (((ks * 4 + q) ^ la) * 8));
#pragma unroll
        for (int ic = 0; ic < 2; ++ic)
#pragma unroll
          for (int dc = 0; dc < 4; ++dc)
            accO[ic][dc] = MFMA(pf[ic], vf[dc], accO[ic][dc]);
      }
    }
#pragma unroll
    for (int ic = 0; ic < 2; ++ic) {
      float r = rs[ic];
      r += __shfl_xor(r, 16);
      r += __shfl_xor(r, 32);
      l_[ic] = l_[ic] * alpha_[ic] + r;
    }
  }

  // epilogue: O / l  (l for row base+t lives in lane t<16)
  const int b = bh >> 4, h = bh & 15;
#pragma unroll
  for (int ic = 0; ic < 2; ++ic)
#pragma unroll
    for (int r = 0; r < 4; ++r) {
      const float inv = RCPF(__shfl(l_[ic], q * 4 + r));
      const size_t rowoff =
          ((size_t)(b * 2048 + qt * 128 + w * 32 + ic * 16 + q * 4 + r)) * 1024 + h * 64;
#pragma unroll
      for (int dc = 0; dc < 4; ++dc)
        ctx[rowoff + dc * 16 + la] = f2bf(accO[ic][dc][r] * inv);
    }
}

// ---------------------------------------------------------------------------
// Buffer schedule (no workspace needed; harness restores d_in before every
// launch, kernels serialize on `stream`):
//   d_out (33.6MB): bX (16.8, current converted activation) | bWq|bWk|bWv (2 each)
//   Xq buf: Qh (16.8) | ctx (16.8)      Xk buf: Kh (16.8) | bWo (2)
//   Xv buf: VTp (16.8)
// Final GEMM overwrites d_out (all prior d_out residents dead by then).
// ---------------------------------------------------------------------------
extern "C" void kernel_launch(void* const* d_in, const int* in_sizes, int n_in,
                              void* d_out, int out_size, void* d_ws, size_t ws_size,
                              hipStream_t stream) {
  const float* Xqf = (const float*)d_in[0];
  const float* Xkf = (const float*)d_in[1];
  const float* Xvf = (const float*)d_in[2];
  const float* Wqf = (const float*)d_in[3];
  const float* Wkf = (const float*)d_in[4];
  const float* Wvf = (const float*)d_in[5];
  const float* Wof = (const float*)d_in[6];

  const size_t TE = 8388608;  // activation elems (4*2048*1024)
  const size_t WE = 1048576;  // weight elems (1024*1024)
  u16* dout16 = (u16*)d_out;
  u16* bX = dout16;
  u16* bWq = dout16 + TE;
  u16* bWk = bWq + WE;
  u16* bWv = bWk + WE;
  u16* Qh = (u16*)d_in[0];
  u16* ctx = Qh + TE;
  u16* Kh = (u16*)d_in[1];
  u16* bWo = Kh + TE;
  u16* VTp = (u16*)d_in[2];

  const float SC = 0.18033688011112042f;  // log2(e)/sqrt(64), folded into Q

  dim3 blk(256);
  dim3 gg(64, 8);  // 8192/128 x 1024/128
  hipLaunchKernelGGL(convert2, dim3(4096), blk, 0, stream, Xqf, bX, (int)(TE / 8), Wqf, bWq, (int)(WE / 8));
  hipLaunchKernelGGL(convert2, dim3(512), blk, 0, stream, Wkf, bWk, (int)(WE / 8), Wvf, bWv, (int)(WE / 8));
  hipLaunchKernelGGL((gemm_bt<1, u16>), gg, blk, 0, stream, bX, bWq, Qh, SC);
  hipLaunchKernelGGL(convert2, dim3(4096), blk, 0, stream, Xkf, bX, (int)(TE / 8), (const float*)nullptr, (u16*)nullptr, 0);
  hipLaunchKernelGGL((gemm_bt<1, u16>), gg, blk, 0, stream, bX, bWk, Kh, 1.0f);
  hipLaunchKernelGGL(convert2, dim3(4096), blk, 0, stream, Xvf, bX, (int)(TE / 8), Wof, bWo, (int)(WE / 8));
  hipLaunchKernelGGL((gemm_bt<2, u16>), gg, blk, 0, stream, bX, bWv, VTp, 1.0f);
  hipLaunchKernelGGL(attn_kernel, dim3(16, 64), blk, 0, stream, Qh, Kh, VTp, ctx);
  hipLaunchKernelGGL((gemm_bt<0, float>), gg, blk, 0, stream, ctx, bWo, (float*)d_out, 1.0f);
}